// Round 6
// baseline (146.907 us; speedup 1.0000x reference)
//
#include <hip/hip_runtime.h>
#include <math.h>

#define DIM 1024
#define NB  256
#define NF  64
#define KS  8          // split-K slices
#define TK  (DIM/KS)   // 128 k per GEMM block
#define PADK 132       // LDS leading dim

// ws layout (total ~3.01 MB):
// thres : [0, 4 KB)
// diag  : [4 KB, 8 KB)        zeroed by memset node, then atomically accumulated
// vmean : [8 KB, 8 KB + 1 MB)
// part  : [+1 MB, +3 MB)      8 x 256 x 256 split-K partials

// ---- K1: blocks 0..255 compute vmean[b]; ALL 1024 blocks compute thres[b] --------
__global__ __launch_bounds__(256)
void k1(const float* __restrict__ vid, const float* __restrict__ emb,
        const float* __restrict__ simw, float* __restrict__ vmean,
        float* __restrict__ thres) {
    int b = blockIdx.x, t = threadIdx.x;

    if (b < NB) {   // vmean[b][d] = mean_f vid[b][f][d]   (the 64 MB HBM read)
        const float* base = vid + (size_t)b * NF * DIM + t * 4;
        float4 a0 = {0.f,0.f,0.f,0.f}, a1 = {0.f,0.f,0.f,0.f};
        #pragma unroll 8
        for (int f = 0; f < NF; f += 2) {
            float4 v0 = *(const float4*)(base + (size_t)f * DIM);
            float4 v1 = *(const float4*)(base + (size_t)(f + 1) * DIM);
            a0.x += v0.x; a0.y += v0.y; a0.z += v0.z; a0.w += v0.w;
            a1.x += v1.x; a1.y += v1.y; a1.z += v1.z; a1.w += v1.w;
        }
        float4 a = { (a0.x + a1.x) * (1.0f/64.0f), (a0.y + a1.y) * (1.0f/64.0f),
                     (a0.z + a1.z) * (1.0f/64.0f), (a0.w + a1.w) * (1.0f/64.0f) };
        *(float4*)(vmean + (size_t)b * DIM + t * 4) = a;
    }

    // thres[b] = mean + simw[b]*std(ddof=1) of sigmoid(emb[b,:]) — hides under vid read
    float4 e = *(const float4*)(emb + (size_t)b * DIM + t * 4);
    float w0 = 1.0f / (1.0f + expf(-e.x));
    float w1 = 1.0f / (1.0f + expf(-e.y));
    float w2 = 1.0f / (1.0f + expf(-e.z));
    float w3 = 1.0f / (1.0f + expf(-e.w));
    double s  = (double)w0 + w1 + w2 + w3;
    double sq = (double)w0*w0 + (double)w1*w1 + (double)w2*w2 + (double)w3*w3;
    #pragma unroll
    for (int off = 32; off > 0; off >>= 1) {
        s  += __shfl_down(s, off);
        sq += __shfl_down(sq, off);
    }
    __shared__ double ls[4], lq[4];
    int wid = t >> 6, lane = t & 63;
    if (lane == 0) { ls[wid] = s; lq[wid] = sq; }
    __syncthreads();
    if (t == 0) {
        double S = ls[0] + ls[1] + ls[2] + ls[3];
        double Q = lq[0] + lq[1] + lq[2] + lq[3];
        double mean = S / DIM;
        double var  = (Q - S * S / DIM) / (DIM - 1);
        if (var < 0.0) var = 0.0;
        thres[b] = (float)(mean + (double)simw[b] * sqrt(var));
    }
}

// ---- K2: 256 blocks x 4 rows: dlw rows, column partials atomically into diag -----
// tanh(y) for y>=0 via 1 - 2/(e^{2y}+1); __expf(inf)=inf -> tanh -> 1 correctly.
__global__ __launch_bounds__(256)
void k2(const float* __restrict__ emb, const float* __restrict__ thres,
        const float* __restrict__ tempw, float* __restrict__ diag) {
    int b = blockIdx.x, t = threadIdx.x;
    float et = expf(tempw[0]);
    float4 th = *(const float4*)(thres + t * 4);      // thres indexed by COLUMN
    float4 acc = {0.f, 0.f, 0.f, 0.f};
    __shared__ float red[4];
    int wid = t >> 6, lane = t & 63;
    #pragma unroll
    for (int rr = 0; rr < 4; ++rr) {
        int r = b * 4 + rr;
        float4 e = *(const float4*)(emb + (size_t)r * DIM + t * 4);
        float w0 = 1.0f / (1.0f + __expf(-e.x));
        float w1 = 1.0f / (1.0f + __expf(-e.y));
        float w2 = 1.0f / (1.0f + __expf(-e.z));
        float w3 = 1.0f / (1.0f + __expf(-e.w));
        float y0 = __expf(et * (w0 - th.x));
        float y1 = __expf(et * (w1 - th.y));
        float y2 = __expf(et * (w2 - th.z));
        float y3 = __expf(et * (w3 - th.w));
        float m0 = (1.0f - 2.0f / (__expf(2.0f * y0) + 1.0f)) * w0;
        float m1 = (1.0f - 2.0f / (__expf(2.0f * y1) + 1.0f)) * w1;
        float m2 = (1.0f - 2.0f / (__expf(2.0f * y2) + 1.0f)) * w2;
        float m3 = (1.0f - 2.0f / (__expf(2.0f * y3) + 1.0f)) * w3;
        float ss = m0*m0 + m1*m1 + m2*m2 + m3*m3;
        #pragma unroll
        for (int off = 32; off > 0; off >>= 1) ss += __shfl_down(ss, off);
        if (lane == 0) red[wid] = ss;
        __syncthreads();
        float rn = 1.0f / (sqrtf(red[0] + red[1] + red[2] + red[3]) + 1e-8f);
        acc.x += m0 * rn; acc.y += m1 * rn; acc.z += m2 * rn; acc.w += m3 * rn;
        __syncthreads();   // guard red[] reuse next row
    }
    atomicAdd(&diag[t * 4 + 0], acc.x);
    atomicAdd(&diag[t * 4 + 1], acc.y);
    atomicAdd(&diag[t * 4 + 2], acc.z);
    atomicAdd(&diag[t * 4 + 3], acc.w);
}

// ---- K4: split-K GEMM, 512 blocks: 64 tiles (8x8 of 32x32) x 8 k-slices ----------
__global__ __launch_bounds__(256)
void k4(const float* __restrict__ txt, const float* __restrict__ diag,
        const float* __restrict__ vmean, float* __restrict__ part) {
    __shared__ float Tt[32][PADK];
    __shared__ float Vt[32][PADK];
    int bx   = blockIdx.x;
    int tile = bx & 63;
    int ks   = bx >> 6;
    int i0 = (tile & 7) * 32, j0 = (tile >> 3) * 32;
    int kb = ks * TK;
    int t  = threadIdx.x;
    int tx = t & 15, ty = t >> 4;
    #pragma unroll
    for (int p = 0; p < 4; ++p) {
        int fid = p * 256 + t;
        int row = fid >> 5;
        int kq  = fid & 31;
        float4 a  = *(const float4*)(txt + (size_t)(i0 + row) * DIM + kb + kq * 4);
        float4 dg = *(const float4*)(diag + kb + kq * 4);
        a.x *= dg.x; a.y *= dg.y; a.z *= dg.z; a.w *= dg.w;
        *(float4*)&Tt[row][kq * 4] = a;
        float4 bb = *(const float4*)(vmean + (size_t)(j0 + row) * DIM + kb + kq * 4);
        *(float4*)&Vt[row][kq * 4] = bb;
    }
    __syncthreads();
    float acc00 = 0.f, acc01 = 0.f, acc10 = 0.f, acc11 = 0.f;
    #pragma unroll
    for (int k4i = 0; k4i < TK / 4; ++k4i) {
        float4 a0 = *(float4*)&Tt[ty * 2 + 0][k4i * 4];
        float4 a1 = *(float4*)&Tt[ty * 2 + 1][k4i * 4];
        float4 b0 = *(float4*)&Vt[tx * 2 + 0][k4i * 4];
        float4 b1 = *(float4*)&Vt[tx * 2 + 1][k4i * 4];
        acc00 = fmaf(a0.x, b0.x, acc00); acc00 = fmaf(a0.y, b0.y, acc00);
        acc00 = fmaf(a0.z, b0.z, acc00); acc00 = fmaf(a0.w, b0.w, acc00);
        acc01 = fmaf(a0.x, b1.x, acc01); acc01 = fmaf(a0.y, b1.y, acc01);
        acc01 = fmaf(a0.z, b1.z, acc01); acc01 = fmaf(a0.w, b1.w, acc01);
        acc10 = fmaf(a1.x, b0.x, acc10); acc10 = fmaf(a1.y, b0.y, acc10);
        acc10 = fmaf(a1.z, b0.z, acc10); acc10 = fmaf(a1.w, b0.w, acc10);
        acc11 = fmaf(a1.x, b1.x, acc11); acc11 = fmaf(a1.y, b1.y, acc11);
        acc11 = fmaf(a1.z, b1.z, acc11); acc11 = fmaf(a1.w, b1.w, acc11);
    }
    size_t base = (size_t)ks * (NB * NB);
    part[base + (size_t)(i0 + ty*2 + 0) * NB + j0 + tx*2 + 0] = acc00;
    part[base + (size_t)(i0 + ty*2 + 0) * NB + j0 + tx*2 + 1] = acc01;
    part[base + (size_t)(i0 + ty*2 + 1) * NB + j0 + tx*2 + 0] = acc10;
    part[base + (size_t)(i0 + ty*2 + 1) * NB + j0 + tx*2 + 1] = acc11;
}

// ---- K5: sum split-K partials + row-wise L2 norm ---------------------------------
__global__ __launch_bounds__(256)
void k5(const float* __restrict__ part, float* __restrict__ out) {
    int i = blockIdx.x, j = threadIdx.x;
    float s = 0.f;
    #pragma unroll
    for (int ks = 0; ks < KS; ++ks)
        s += part[(size_t)ks * (NB * NB) + (size_t)i * NB + j];
    float ss = s * s;
    #pragma unroll
    for (int off = 32; off > 0; off >>= 1) ss += __shfl_down(ss, off);
    __shared__ float red[4];
    int wid = j >> 6, lane = j & 63;
    if (lane == 0) red[wid] = ss;
    __syncthreads();
    float norm = sqrtf(red[0] + red[1] + red[2] + red[3]);
    out[(size_t)i * NB + j] = s / (norm + 1e-8f);
}

extern "C" void kernel_launch(void* const* d_in, const int* in_sizes, int n_in,
                              void* d_out, int out_size, void* d_ws, size_t ws_size,
                              hipStream_t stream) {
    const float* txt   = (const float*)d_in[0];   // [256,1024]
    const float* vid   = (const float*)d_in[1];   // [256,64,1024]
    const float* emb   = (const float*)d_in[2];   // [1024,1024]
    const float* simw  = (const float*)d_in[3];   // [1,1024]
    const float* tempw = (const float*)d_in[4];   // [1,1]
    float* out = (float*)d_out;                   // [256,256]

    char* ws = (char*)d_ws;
    float* thres = (float*)(ws);                                   // 4 KB
    float* diag  = (float*)(ws + 4096);                            // 4 KB
    float* vmean = (float*)(ws + 8192);                            // 1 MB
    float* part  = (float*)(ws + 8192 + (1u << 20));               // 2 MB

    hipMemsetAsync(diag, 0, DIM * sizeof(float), stream);          // atomic target
    k1<<<1024, 256, 0, stream>>>(vid, emb, simw, vmean, thres);
    k2<<<256,  256, 0, stream>>>(emb, thres, tempw, diag);
    k4<<<512,  256, 0, stream>>>(txt, diag, vmean, part);
    k5<<<256,  256, 0, stream>>>(part, out);
}

// Round 7
// 123.266 us; speedup vs baseline: 1.1918x; 1.1918x over previous
//
#include <hip/hip_runtime.h>
#include <math.h>

#define DIM 1024
#define NB  256
#define NF  64
#define KS  8          // split-K slices
#define TK  (DIM/KS)   // 128 k per GEMM block
#define PADK 132       // LDS leading dim

// ws layout (total ~4.01 MB, every byte written before read each call):
// thres : [0, 4 KB)
// diag  : [4 KB, 8 KB)
// cpart : [8 KB, 8 KB + 1 MB)    256 x 1024 partial col sums of dlw (4 rows/block)
// vmean : [+1 MB, +2 MB)         256 x 1024
// part  : [+2 MB, +4 MB)         8 x 256 x 256 split-K partials

// ---- K1: blocks 0..255 compute vmean[b]; ALL 1024 blocks compute thres[b] --------
__global__ __launch_bounds__(256)
void k1(const float* __restrict__ vid, const float* __restrict__ emb,
        const float* __restrict__ simw, float* __restrict__ vmean,
        float* __restrict__ thres) {
    int b = blockIdx.x, t = threadIdx.x;

    if (b < NB) {   // vmean[b][d] = mean_f vid[b][f][d]   (the 64 MB HBM read)
        const float* base = vid + (size_t)b * NF * DIM + t * 4;
        float4 a0 = {0.f,0.f,0.f,0.f}, a1 = {0.f,0.f,0.f,0.f};
        #pragma unroll 8
        for (int f = 0; f < NF; f += 2) {
            float4 v0 = *(const float4*)(base + (size_t)f * DIM);
            float4 v1 = *(const float4*)(base + (size_t)(f + 1) * DIM);
            a0.x += v0.x; a0.y += v0.y; a0.z += v0.z; a0.w += v0.w;
            a1.x += v1.x; a1.y += v1.y; a1.z += v1.z; a1.w += v1.w;
        }
        float4 a = { (a0.x + a1.x) * (1.0f/64.0f), (a0.y + a1.y) * (1.0f/64.0f),
                     (a0.z + a1.z) * (1.0f/64.0f), (a0.w + a1.w) * (1.0f/64.0f) };
        *(float4*)(vmean + (size_t)b * DIM + t * 4) = a;
    }

    // thres[b] = mean + simw[b]*std(ddof=1) of sigmoid(emb[b,:]) — hides under vid read
    float4 e = *(const float4*)(emb + (size_t)b * DIM + t * 4);
    float w0 = 1.0f / (1.0f + expf(-e.x));
    float w1 = 1.0f / (1.0f + expf(-e.y));
    float w2 = 1.0f / (1.0f + expf(-e.z));
    float w3 = 1.0f / (1.0f + expf(-e.w));
    double s  = (double)w0 + w1 + w2 + w3;
    double sq = (double)w0*w0 + (double)w1*w1 + (double)w2*w2 + (double)w3*w3;
    #pragma unroll
    for (int off = 32; off > 0; off >>= 1) {
        s  += __shfl_down(s, off);
        sq += __shfl_down(sq, off);
    }
    __shared__ double ls[4], lq[4];
    int wid = t >> 6, lane = t & 63;
    if (lane == 0) { ls[wid] = s; lq[wid] = sq; }
    __syncthreads();
    if (t == 0) {
        double S = ls[0] + ls[1] + ls[2] + ls[3];
        double Q = lq[0] + lq[1] + lq[2] + lq[3];
        double mean = S / DIM;
        double var  = (Q - S * S / DIM) / (DIM - 1);
        if (var < 0.0) var = 0.0;
        thres[b] = (float)(mean + (double)simw[b] * sqrt(var));
    }
}

// ---- K2: 256 blocks x 4 rows: dlw rows + register-accumulated partial col sums ----
// tanh(y) for y>=0 via 1 - 2/(e^{2y}+1); __expf(inf)=inf -> tanh -> 1 correctly.
__global__ __launch_bounds__(256)
void k2(const float* __restrict__ emb, const float* __restrict__ thres,
        const float* __restrict__ tempw, float* __restrict__ cpart) {
    int b = blockIdx.x, t = threadIdx.x;
    float et = expf(tempw[0]);
    float4 th = *(const float4*)(thres + t * 4);      // thres indexed by COLUMN
    float4 acc = {0.f, 0.f, 0.f, 0.f};
    __shared__ float red[4];
    int wid = t >> 6, lane = t & 63;
    #pragma unroll
    for (int rr = 0; rr < 4; ++rr) {
        int r = b * 4 + rr;
        float4 e = *(const float4*)(emb + (size_t)r * DIM + t * 4);
        float w0 = 1.0f / (1.0f + __expf(-e.x));
        float w1 = 1.0f / (1.0f + __expf(-e.y));
        float w2 = 1.0f / (1.0f + __expf(-e.z));
        float w3 = 1.0f / (1.0f + __expf(-e.w));
        float y0 = __expf(et * (w0 - th.x));
        float y1 = __expf(et * (w1 - th.y));
        float y2 = __expf(et * (w2 - th.z));
        float y3 = __expf(et * (w3 - th.w));
        float m0 = (1.0f - 2.0f / (__expf(2.0f * y0) + 1.0f)) * w0;
        float m1 = (1.0f - 2.0f / (__expf(2.0f * y1) + 1.0f)) * w1;
        float m2 = (1.0f - 2.0f / (__expf(2.0f * y2) + 1.0f)) * w2;
        float m3 = (1.0f - 2.0f / (__expf(2.0f * y3) + 1.0f)) * w3;
        float ss = m0*m0 + m1*m1 + m2*m2 + m3*m3;
        #pragma unroll
        for (int off = 32; off > 0; off >>= 1) ss += __shfl_down(ss, off);
        if (lane == 0) red[wid] = ss;
        __syncthreads();
        float rn = 1.0f / (sqrtf(red[0] + red[1] + red[2] + red[3]) + 1e-8f);
        acc.x += m0 * rn; acc.y += m1 * rn; acc.z += m2 * rn; acc.w += m3 * rn;
        __syncthreads();   // guard red[] reuse next row
    }
    *(float4*)(cpart + (size_t)b * DIM + t * 4) = acc;
}

// ---- K3: diag[c] = sum over 256 cpart rows; 64 blocks x 16 cols -------------------
__global__ __launch_bounds__(256)
void k3(const float* __restrict__ cpart, float* __restrict__ diag) {
    int b = blockIdx.x;
    int t = threadIdx.x;
    int c16 = t & 15, rg = t >> 4;   // 16 row-groups x 16 rows
    int col = b * 16 + c16;
    float s = 0.f;
    #pragma unroll
    for (int i = 0; i < 16; ++i)
        s += cpart[(size_t)(rg * 16 + i) * DIM + col];
    __shared__ float red[16][16];
    red[rg][c16] = s;
    __syncthreads();
    if (rg == 0) {
        float tot = 0.f;
        #pragma unroll
        for (int g = 0; g < 16; ++g) tot += red[g][c16];
        diag[col] = tot;
    }
}

// ---- K4: split-K GEMM, 512 blocks: 64 tiles (8x8 of 32x32) x 8 k-slices ----------
__global__ __launch_bounds__(256)
void k4(const float* __restrict__ txt, const float* __restrict__ diag,
        const float* __restrict__ vmean, float* __restrict__ part) {
    __shared__ float Tt[32][PADK];
    __shared__ float Vt[32][PADK];
    int bx   = blockIdx.x;
    int tile = bx & 63;
    int ks   = bx >> 6;
    int i0 = (tile & 7) * 32, j0 = (tile >> 3) * 32;
    int kb = ks * TK;
    int t  = threadIdx.x;
    int tx = t & 15, ty = t >> 4;
    #pragma unroll
    for (int p = 0; p < 4; ++p) {
        int fid = p * 256 + t;
        int row = fid >> 5;
        int kq  = fid & 31;
        float4 a  = *(const float4*)(txt + (size_t)(i0 + row) * DIM + kb + kq * 4);
        float4 dg = *(const float4*)(diag + kb + kq * 4);
        a.x *= dg.x; a.y *= dg.y; a.z *= dg.z; a.w *= dg.w;
        *(float4*)&Tt[row][kq * 4] = a;
        float4 bb = *(const float4*)(vmean + (size_t)(j0 + row) * DIM + kb + kq * 4);
        *(float4*)&Vt[row][kq * 4] = bb;
    }
    __syncthreads();
    float acc00 = 0.f, acc01 = 0.f, acc10 = 0.f, acc11 = 0.f;
    #pragma unroll
    for (int k4i = 0; k4i < TK / 4; ++k4i) {
        float4 a0 = *(float4*)&Tt[ty * 2 + 0][k4i * 4];
        float4 a1 = *(float4*)&Tt[ty * 2 + 1][k4i * 4];
        float4 b0 = *(float4*)&Vt[tx * 2 + 0][k4i * 4];
        float4 b1 = *(float4*)&Vt[tx * 2 + 1][k4i * 4];
        acc00 = fmaf(a0.x, b0.x, acc00); acc00 = fmaf(a0.y, b0.y, acc00);
        acc00 = fmaf(a0.z, b0.z, acc00); acc00 = fmaf(a0.w, b0.w, acc00);
        acc01 = fmaf(a0.x, b1.x, acc01); acc01 = fmaf(a0.y, b1.y, acc01);
        acc01 = fmaf(a0.z, b1.z, acc01); acc01 = fmaf(a0.w, b1.w, acc01);
        acc10 = fmaf(a1.x, b0.x, acc10); acc10 = fmaf(a1.y, b0.y, acc10);
        acc10 = fmaf(a1.z, b0.z, acc10); acc10 = fmaf(a1.w, b0.w, acc10);
        acc11 = fmaf(a1.x, b1.x, acc11); acc11 = fmaf(a1.y, b1.y, acc11);
        acc11 = fmaf(a1.w, b1.w, acc11); acc11 = fmaf(a1.z, b1.z, acc11);
    }
    size_t base = (size_t)ks * (NB * NB);
    part[base + (size_t)(i0 + ty*2 + 0) * NB + j0 + tx*2 + 0] = acc00;
    part[base + (size_t)(i0 + ty*2 + 0) * NB + j0 + tx*2 + 1] = acc01;
    part[base + (size_t)(i0 + ty*2 + 1) * NB + j0 + tx*2 + 0] = acc10;
    part[base + (size_t)(i0 + ty*2 + 1) * NB + j0 + tx*2 + 1] = acc11;
}

// ---- K5: sum split-K partials + row-wise L2 norm ---------------------------------
__global__ __launch_bounds__(256)
void k5(const float* __restrict__ part, float* __restrict__ out) {
    int i = blockIdx.x, j = threadIdx.x;
    float s = 0.f;
    #pragma unroll
    for (int ks = 0; ks < KS; ++ks)
        s += part[(size_t)ks * (NB * NB) + (size_t)i * NB + j];
    float ss = s * s;
    #pragma unroll
    for (int off = 32; off > 0; off >>= 1) ss += __shfl_down(ss, off);
    __shared__ float red[4];
    int wid = j >> 6, lane = j & 63;
    if (lane == 0) red[wid] = ss;
    __syncthreads();
    float norm = sqrtf(red[0] + red[1] + red[2] + red[3]);
    out[(size_t)i * NB + j] = s / (norm + 1e-8f);
}

extern "C" void kernel_launch(void* const* d_in, const int* in_sizes, int n_in,
                              void* d_out, int out_size, void* d_ws, size_t ws_size,
                              hipStream_t stream) {
    const float* txt   = (const float*)d_in[0];   // [256,1024]
    const float* vid   = (const float*)d_in[1];   // [256,64,1024]
    const float* emb   = (const float*)d_in[2];   // [1024,1024]
    const float* simw  = (const float*)d_in[3];   // [1,1024]
    const float* tempw = (const float*)d_in[4];   // [1,1]
    float* out = (float*)d_out;                   // [256,256]

    char* ws = (char*)d_ws;
    float* thres = (float*)(ws);                                   // 4 KB
    float* diag  = (float*)(ws + 4096);                            // 4 KB
    float* cpart = (float*)(ws + 8192);                            // 1 MB
    float* vmean = (float*)(ws + 8192 + (1u << 20));               // 1 MB
    float* part  = (float*)(ws + 8192 + (2u << 20));               // 2 MB

    k1<<<1024, 256, 0, stream>>>(vid, emb, simw, vmean, thres);
    k2<<<256,  256, 0, stream>>>(emb, thres, tempw, cpart);
    k3<<<64,   256, 0, stream>>>(cpart, diag);
    k4<<<512,  256, 0, stream>>>(txt, diag, vmean, part);
    k5<<<256,  256, 0, stream>>>(part, out);
}